// Round 4
// baseline (63199.347 us; speedup 1.0000x reference)
//
#include <hip/hip_runtime.h>
#include <hip/hip_bf16.h>
#include <stdint.h>

// Problem constants
#define N_B     64
#define T_STEPS 1024
#define T1      1025
#define VOCAB   10000
#define DIM     512
#define HID     512
#define FOURH   2048
#define SBLK    8       // scan blocks (batch-split: 8 rows each) -> 1 per XCD
#define ROWS    8       // batch rows per scan block
#define PADU    524     // u32 stride per LDS h row (16B aligned, spreads banks)

typedef unsigned short u16;
typedef unsigned int   u32;
typedef unsigned long long u64;
typedef short bf16x8 __attribute__((ext_vector_type(8)));   // 8 bf16 = 4 VGPRs
typedef float f32x4  __attribute__((ext_vector_type(4)));   // 16x16 MFMA acc
typedef float f32x16 __attribute__((ext_vector_type(16)));  // 32x32 MFMA acc

__device__ __forceinline__ float bf2f(u16 x){
  union { u32 u; float f; } v; v.u = ((u32)x) << 16; return v.f;
}
__device__ __forceinline__ u16 f2bf(float f){
  union { float f; u32 u; } v; v.f = f;
  u32 u = v.u;
  return (u16)((u + 0x7FFFu + ((u >> 16) & 1u)) >> 16);  // RNE
}
__device__ __forceinline__ bf16x8 ldfrag(const u16* p){
  union { uint4 q; bf16x8 s; } v; v.q = *(const uint4*)p; return v.s;
}
__device__ __forceinline__ float fsig(float x){
  return 1.0f / (1.0f + exp2f(x * -1.44269504f));
}
__device__ __forceinline__ float ftanh(float x){
  return 1.0f - 2.0f / (1.0f + exp2f(x * 2.88539008f));  // saturates at +/-1
}
// pack h into (hi16 | lo16<<16) bf16 pair
__device__ __forceinline__ u32 packhl(float h){
  u32 hb = f2bf(h);
  float rem = h - bf2f((u16)hb);
  u32 lb = f2bf(rem);
  return hb | (lb << 16);
}

// ---- transpose+convert Wx, Wh (512 x 2048 fp32) -> bf16 (2048 x 512) ----
__global__ void k_transpose(const float* __restrict__ Wx, const float* __restrict__ Wh,
                            u16* __restrict__ WxT, u16* __restrict__ WhT){
  int b = blockIdx.x;
  const float* src = Wx; u16* dst = WxT;
  if (b >= 512){ src = Wh; dst = WhT; b -= 512; }
  int id = b * 256 + threadIdx.x;       // 131072 ids: 2048 cols x 64 k-chunks
  int n  = id & (FOURH - 1);            // source col (consecutive per lane -> coalesced)
  int kc = (id >> 11) << 3;             // k chunk of 8
  u32 w[4];
  #pragma unroll
  for (int j = 0; j < 4; j++){
    u32 lo = (u32)f2bf(src[(kc + 2*j    ) * FOURH + n]);
    u32 hi = (u32)f2bf(src[(kc + 2*j + 1) * FOURH + n]);
    w[j] = lo | (hi << 16);
  }
  uint4 q; q.x = w[0]; q.y = w[1]; q.z = w[2]; q.w = w[3];
  *(uint4*)(dst + n * DIM + kc) = q;
}

// ---- convert W_embed (10000 x 512 fp32) -> bf16, same layout ----
__global__ void k_wemb(const float* __restrict__ Wemb, u16* __restrict__ We16){
  int i = blockIdx.x * 256 + threadIdx.x;        // 2,560,000 ids, 2 elems each
  float2 f = *(const float2*)(Wemb + 2 * i);
  u32 pk = (u32)f2bf(f.x) | ((u32)f2bf(f.y) << 16);
  *(u32*)(We16 + 2 * i) = pk;
}

// ---- E = W_embed @ Wx + b  (10000 x 2048, bf16) ----
__launch_bounds__(256)
__global__ void k_egemm(const u16* __restrict__ Wemb, const u16* __restrict__ WxT,
                        const float* __restrict__ bias, u16* __restrict__ E){
  int nb = blockIdx.x;            // 0..15  -> cols nb*128
  int mb = blockIdx.y;            // 0..78  -> rows mb*128
  int wv   = threadIdx.x >> 6;
  int lane = threadIdx.x & 63;
  int l31 = lane & 31, hi5 = lane >> 5;
  int mrow = mb * 128 + wv * 32 + l31;
  int mcl  = mrow < VOCAB ? mrow : VOCAB - 1;
  const u16* ap  = Wemb + (u32)mcl * DIM + hi5 * 8;
  const u16* bp0 = WxT + (u32)(nb * 128 +  0 + l31) * DIM + hi5 * 8;
  const u16* bp1 = bp0 + 32 * DIM;
  const u16* bp2 = bp0 + 64 * DIM;
  const u16* bp3 = bp0 + 96 * DIM;
  f32x16 acc[4] = {};
  for (int ks = 0; ks < 32; ks++){
    bf16x8 av = ldfrag(ap);  ap  += 16;
    bf16x8 b0 = ldfrag(bp0); bp0 += 16;
    bf16x8 b1 = ldfrag(bp1); bp1 += 16;
    bf16x8 b2 = ldfrag(bp2); bp2 += 16;
    bf16x8 b3 = ldfrag(bp3); bp3 += 16;
    acc[0] = __builtin_amdgcn_mfma_f32_32x32x16_bf16(av, b0, acc[0], 0, 0, 0);
    acc[1] = __builtin_amdgcn_mfma_f32_32x32x16_bf16(av, b1, acc[1], 0, 0, 0);
    acc[2] = __builtin_amdgcn_mfma_f32_32x32x16_bf16(av, b2, acc[2], 0, 0, 0);
    acc[3] = __builtin_amdgcn_mfma_f32_32x32x16_bf16(av, b3, acc[3], 0, 0, 0);
  }
  int rbase = mb * 128 + wv * 32 + 4 * hi5;
  #pragma unroll
  for (int nt = 0; nt < 4; nt++){
    int col = nb * 128 + nt * 32 + l31;
    float bv = bias[col];
    #pragma unroll
    for (int r = 0; r < 16; r++){
      int row = rbase + (r & 3) + 8 * (r >> 2);
      if (row < VOCAB) E[(u32)row * FOURH + col] = f2bf(acc[nt][r] + bv);
    }
  }
}

// ---- persistent LSTM scan: BATCH-SPLIT, zero inter-block communication ----
// 8 blocks x 512 threads (8 waves). Block b owns batch rows [b*8, b*8+8).
// h state lives in LDS (double-buffered, packed bf16 hi|lo), one
// __syncthreads() per step. All 2048 gate columns computed per block.
// Wave w owns hidden dims [w*64, w*64+64) as 16 MFMA col-tiles:
//   (g2 in 0..3 = gate i/f/o/g, cq in 0..1, ch in 0..1)
//   gate col = g2*512 + w*64 + cq*32 + 2*li + ch   (parity tiling: one u32
//   E-load covers both ch tiles; h/out writes become contiguous pairs)
// MFMA 16x16x32: A(h): row=l&15 -> rr=l&7, k=(l>>4)*8+j (from LDS, unpack
// hi/lo); B(Wh): col=l&15, k=(l>>4)*8+j (WhT[col][k] layout, k-contiguous);
// C/D: col=l&15, row=(l>>4)*4+reg -> rr=(lg&1)*4+reg. Rows 8..15 duplicate
// rows 0..7 (same data, results discarded) - M-waste is free since per-block
// MFMA count is independent of row count.
__launch_bounds__(512, 2)
__global__ void k_scan(const int* __restrict__ cap, const u16* __restrict__ E,
                       const u16* __restrict__ WhT, const float* __restrict__ h0,
                       float* __restrict__ out){
  __shared__ __align__(16) u32 hlds[2][ROWS][PADU];  // 33.5 KB: packed h (hi|lo<<16)

  const int b   = blockIdx.x;
  const int tid = threadIdx.x;
  const int w   = tid >> 6;             // wave 0..7
  const int l   = tid & 63;
  const int li  = l & 15, lg = l >> 4;
  const int rbase = (lg & 1) * 4;       // C rows rr = rbase + reg

  // --- h0 -> LDS buf0 (packed hi/lo bf16) ---
  for (int i = tid; i < ROWS * HID; i += 512){
    int r = i >> 9, d = i & 511;
    float f = h0[(b * ROWS + r) * HID + d];
    hlds[0][r][d] = packhl(f);
  }

  // Wh fragment base offsets (u16 units): col(cq,ch)*DIM + lg*8; the g2 part
  // (g2*512*DIM) is added as a compile-time constant in the K-loop.
  u32 wbo[2][2];
  #pragma unroll
  for (int cq = 0; cq < 2; cq++)
    #pragma unroll
    for (int ch = 0; ch < 2; ch++)
      wbo[cq][ch] = (u32)(w * 64 + cq * 32 + 2 * li + ch) * DIM + lg * 8;

  // --- caps + E prefetch for t=0; capn for t=1 ---
  int capc[4], capn[4];
  #pragma unroll
  for (int j = 0; j < 4; j++){
    capc[j] = cap[(b * ROWS + rbase + j) * T1];
    capn[j] = cap[(b * ROWS + rbase + j) * T1 + 1];
  }
  u32 ev[8][4];   // [g2*2+cq][reg] : u32 covers cols (2li, 2li+1) = (ch0, ch1)
  #pragma unroll
  for (int g2 = 0; g2 < 4; g2++)
    #pragma unroll
    for (int cq = 0; cq < 2; cq++)
      #pragma unroll
      for (int j = 0; j < 4; j++)
        ev[g2*2+cq][j] = *(const u32*)(E + (u32)capc[j] * FOURH
                                         + g2 * 512 + w * 64 + cq * 32 + 2 * li);

  float cst[16];  // c-state [cq*8 + ch*4 + reg] (all lanes track all 4 regs)
  #pragma unroll
  for (int i = 0; i < 16; i++) cst[i] = 0.f;

  __syncthreads();

  for (int t = 0; t < T_STEPS; t++){
    const int cur = t & 1, nxt = cur ^ 1;

    // ---- C-init from prefetched E (xW + b term) ----
    f32x4 acc[8][2];   // [g2*2+cq][ch]
    #pragma unroll
    for (int g2 = 0; g2 < 4; g2++)
      #pragma unroll
      for (int cq = 0; cq < 2; cq++)
        #pragma unroll
        for (int j = 0; j < 4; j++){
          u32 d = ev[g2*2+cq][j];
          acc[g2*2+cq][0][j] = bf2f((u16)(d & 0xFFFFu));
          acc[g2*2+cq][1][j] = bf2f((u16)(d >> 16));
        }

    // ---- issue E prefetch for t+1 (in place; ev regs just went dead) ----
    #pragma unroll
    for (int g2 = 0; g2 < 4; g2++)
      #pragma unroll
      for (int cq = 0; cq < 2; cq++)
        #pragma unroll
        for (int j = 0; j < 4; j++)
          ev[g2*2+cq][j] = *(const u32*)(E + (u32)capn[j] * FOURH
                                           + g2 * 512 + w * 64 + cq * 32 + 2 * li);
    // cap for t+2 (clamped; consumed next iteration)
    {
      int tn = (t + 2 <= T_STEPS) ? t + 2 : T_STEPS;
      #pragma unroll
      for (int j = 0; j < 4; j++)
        capn[j] = cap[(b * ROWS + rbase + j) * T1 + tn];
    }

    // ---- K-loop: acc += h(16x32k) . Wh(32k x 16col), hi + lo ----
    #pragma unroll 2
    for (int ks = 0; ks < 16; ks++){
      const u32* ap = &hlds[cur][l & 7][ks * 32 + lg * 8];
      uint4 pa = *(const uint4*)ap;        // ds_read_b128: dims k+0..3 packed
      uint4 pb = *(const uint4*)(ap + 4);  // dims k+4..7
      union { u32 u[4]; bf16x8 s; } uh, ul;
      uh.u[0] = (pa.x & 0xFFFFu) | (pa.y << 16);        // (hi0, hi1)
      uh.u[1] = (pa.z & 0xFFFFu) | (pa.w << 16);        // (hi2, hi3)
      uh.u[2] = (pb.x & 0xFFFFu) | (pb.y << 16);        // (hi4, hi5)
      uh.u[3] = (pb.z & 0xFFFFu) | (pb.w << 16);        // (hi6, hi7)
      ul.u[0] = (pa.x >> 16) | (pa.y & 0xFFFF0000u);    // (lo0, lo1)
      ul.u[1] = (pa.z >> 16) | (pa.w & 0xFFFF0000u);    // (lo2, lo3)
      ul.u[2] = (pb.x >> 16) | (pb.y & 0xFFFF0000u);    // (lo4, lo5)
      ul.u[3] = (pb.z >> 16) | (pb.w & 0xFFFF0000u);    // (lo6, lo7)
      bf16x8 ahf = uh.s, alf = ul.s;

      #pragma unroll
      for (int cq = 0; cq < 2; cq++){
        bf16x8 bfr[8];
        #pragma unroll
        for (int g2 = 0; g2 < 4; g2++){
          bfr[g2*2+0] = ldfrag(WhT + wbo[cq][0] + (u32)g2 * (512*DIM) + ks * 32);
          bfr[g2*2+1] = ldfrag(WhT + wbo[cq][1] + (u32)g2 * (512*DIM) + ks * 32);
        }
        #pragma unroll
        for (int g2 = 0; g2 < 4; g2++){
          acc[g2*2+cq][0] = __builtin_amdgcn_mfma_f32_16x16x32_bf16(ahf, bfr[g2*2+0], acc[g2*2+cq][0], 0, 0, 0);
          acc[g2*2+cq][1] = __builtin_amdgcn_mfma_f32_16x16x32_bf16(ahf, bfr[g2*2+1], acc[g2*2+cq][1], 0, 0, 0);
        }
        #pragma unroll
        for (int g2 = 0; g2 < 4; g2++){
          acc[g2*2+cq][0] = __builtin_amdgcn_mfma_f32_16x16x32_bf16(alf, bfr[g2*2+0], acc[g2*2+cq][0], 0, 0, 0);
          acc[g2*2+cq][1] = __builtin_amdgcn_mfma_f32_16x16x32_bf16(alf, bfr[g2*2+1], acc[g2*2+cq][1], 0, 0, 0);
        }
      }
    }

    // ---- LSTM cell + h/out writes ----
    #pragma unroll
    for (int cq = 0; cq < 2; cq++){
      float hch[2][4];
      #pragma unroll
      for (int ch = 0; ch < 2; ch++)
        #pragma unroll
        for (int j = 0; j < 4; j++){
          float ai = acc[0*2+cq][ch][j], af = acc[1*2+cq][ch][j];
          float ao = acc[2*2+cq][ch][j], ag = acc[3*2+cq][ch][j];
          float ig = fsig(ai), fg = fsig(af), og = fsig(ao), gg = ftanh(ag);
          float cc = cst[cq*8 + ch*4 + j];
          cc = fg * cc + ig * gg;
          cst[cq*8 + ch*4 + j] = cc;
          hch[ch][j] = og * ftanh(cc);
        }
      if (lg < 2){   // rows rr = lg*4 + j, written exactly once
        #pragma unroll
        for (int j = 0; j < 4; j++){
          int rr = lg * 4 + j;
          u64 pk2 = (u64)packhl(hch[0][j]) | ((u64)packhl(hch[1][j]) << 32);
          *(u64*)&hlds[nxt][rr][w * 64 + cq * 32 + 2 * li] = pk2;
          union { float f[2]; u64 u; } o2;
          o2.f[0] = hch[0][j]; o2.f[1] = hch[1][j];
          __builtin_nontemporal_store(o2.u,
            (u64*)(out + (u32)(b * ROWS + rr) * (T_STEPS * HID)
                       + (u32)t * HID + w * 64 + cq * 32 + 2 * li));
        }
      }
    }

    __syncthreads();   // hlds[nxt] complete -> next step may read it
  }
}

extern "C" void kernel_launch(void* const* d_in, const int* in_sizes, int n_in,
                              void* d_out, int out_size, void* d_ws, size_t ws_size,
                              hipStream_t stream){
  const int*   cap  = (const int*)d_in[0];
  const float* h0   = (const float*)d_in[1];
  const float* Wemb = (const float*)d_in[2];
  const float* Wx   = (const float*)d_in[3];
  const float* Wh   = (const float*)d_in[4];
  const float* bias = (const float*)d_in[5];
  float* out = (float*)d_out;

  char* ws = (char*)d_ws;
  const size_t OFF_E    = 0;
  const size_t OFF_WXT  = OFF_E    + (size_t)VOCAB * FOURH * 2;   // 40,960,000
  const size_t OFF_WHT  = OFF_WXT  + (size_t)FOURH * DIM * 2;     // +2 MiB
  const size_t OFF_WE16 = OFF_WHT  + (size_t)FOURH * DIM * 2;     // +2 MiB

  u16* E    = (u16*)(ws + OFF_E);
  u16* WxT  = (u16*)(ws + OFF_WXT);
  u16* WhT  = (u16*)(ws + OFF_WHT);
  u16* We16 = (u16*)(ws + OFF_WE16);

  hipLaunchKernelGGL(k_transpose, dim3(1024),   dim3(256), 0, stream, Wx, Wh, WxT, WhT);
  hipLaunchKernelGGL(k_wemb,      dim3(10000),  dim3(256), 0, stream, Wemb, We16);
  hipLaunchKernelGGL(k_egemm,     dim3(16, 79), dim3(256), 0, stream, We16, WxT, bias, E);
  hipLaunchKernelGGL(k_scan,      dim3(SBLK),   dim3(512), 0, stream, cap, E, WhT, h0, out);
}

// Round 6
// 4355.195 us; speedup vs baseline: 14.5113x; 14.5113x over previous
//
#include <hip/hip_runtime.h>
#include <hip/hip_bf16.h>
#include <stdint.h>

// Problem constants
#define N_B     64
#define T_STEPS 1024
#define T1      1025
#define VOCAB   10000
#define DIM     512
#define HID     512
#define FOURH   2048
#define SBLK    64      // scan blocks: 8 groups (8 batch rows each) x 8 dim-slices
#define RPG     8       // batch rows per group
#define LPAD    520     // u16 row stride in LDS h planes (1040 B = 65*16)
#define FLGSTR  32      // u32 stride between per-block flags (128 B line each)

typedef unsigned short u16;
typedef unsigned int   u32;
typedef unsigned long long u64;
typedef short bf16x8 __attribute__((ext_vector_type(8)));   // 8 bf16 = 4 VGPRs
typedef float f32x4  __attribute__((ext_vector_type(4)));   // 16x16 MFMA acc
typedef float f32x16 __attribute__((ext_vector_type(16)));  // 32x32 MFMA acc
typedef u32  u32x4  __attribute__((ext_vector_type(4)));

__device__ __forceinline__ float bf2f(u16 x){
  union { u32 u; float f; } v; v.u = ((u32)x) << 16; return v.f;
}
__device__ __forceinline__ u16 f2bf(float f){
  union { float f; u32 u; } v; v.f = f;
  u32 u = v.u;
  return (u16)((u + 0x7FFFu + ((u >> 16) & 1u)) >> 16);  // RNE
}
__device__ __forceinline__ bf16x8 ldfrag(const u16* p){
  union { u32x4 q; bf16x8 s; } v; v.q = *(const u32x4*)p; return v.s;
}
__device__ __forceinline__ float fsig(float x){
  return 1.0f / (1.0f + exp2f(x * -1.44269504f));
}
__device__ __forceinline__ float ftanh(float x){
  return 1.0f - 2.0f / (1.0f + exp2f(x * 2.88539008f));  // saturates at +/-1
}
// pack h into u32: low16 = bf16 hi, high16 = bf16 lo (residual)
__device__ __forceinline__ u32 packhl(float h){
  u32 hb = f2bf(h);
  float rem = h - bf2f((u16)hb);
  u32 lb = f2bf(rem);
  return hb | (lb << 16);
}

// ---- transpose+convert Wx, Wh (512 x 2048 fp32) -> bf16 (2048 x 512) ----
__global__ void k_transpose(const float* __restrict__ Wx, const float* __restrict__ Wh,
                            u16* __restrict__ WxT, u16* __restrict__ WhT){
  int b = blockIdx.x;
  const float* src = Wx; u16* dst = WxT;
  if (b >= 512){ src = Wh; dst = WhT; b -= 512; }
  int id = b * 256 + threadIdx.x;       // 131072 ids: 2048 cols x 64 k-chunks
  int n  = id & (FOURH - 1);            // source col (consecutive per lane -> coalesced)
  int kc = (id >> 11) << 3;             // k chunk of 8
  u32 w[4];
  #pragma unroll
  for (int j = 0; j < 4; j++){
    u32 lo = (u32)f2bf(src[(kc + 2*j    ) * FOURH + n]);
    u32 hi = (u32)f2bf(src[(kc + 2*j + 1) * FOURH + n]);
    w[j] = lo | (hi << 16);
  }
  uint4 q; q.x = w[0]; q.y = w[1]; q.z = w[2]; q.w = w[3];
  *(uint4*)(dst + n * DIM + kc) = q;
}

// ---- convert W_embed (10000 x 512 fp32) -> bf16, same layout ----
__global__ void k_wemb(const float* __restrict__ Wemb, u16* __restrict__ We16){
  int i = blockIdx.x * 256 + threadIdx.x;        // 2,560,000 ids, 2 elems each
  float2 f = *(const float2*)(Wemb + 2 * i);
  u32 pk = (u32)f2bf(f.x) | ((u32)f2bf(f.y) << 16);
  *(u32*)(We16 + 2 * i) = pk;
}

// ---- init flags ----
__global__ void k_init(u32* flags){
  int i = blockIdx.x * 256 + threadIdx.x;   // 2048
  flags[i] = 0;
}

// ---- E = W_embed @ Wx + b  (10000 x 2048, bf16) ----
__launch_bounds__(256)
__global__ void k_egemm(const u16* __restrict__ Wemb, const u16* __restrict__ WxT,
                        const float* __restrict__ bias, u16* __restrict__ E){
  int nb = blockIdx.x;            // 0..15  -> cols nb*128
  int mb = blockIdx.y;            // 0..78  -> rows mb*128
  int wv   = threadIdx.x >> 6;
  int lane = threadIdx.x & 63;
  int l31 = lane & 31, hi5 = lane >> 5;
  int mrow = mb * 128 + wv * 32 + l31;
  int mcl  = mrow < VOCAB ? mrow : VOCAB - 1;
  const u16* ap  = Wemb + (u32)mcl * DIM + hi5 * 8;
  const u16* bp0 = WxT + (u32)(nb * 128 +  0 + l31) * DIM + hi5 * 8;
  const u16* bp1 = bp0 + 32 * DIM;
  const u16* bp2 = bp0 + 64 * DIM;
  const u16* bp3 = bp0 + 96 * DIM;
  f32x16 acc[4] = {};
  for (int ks = 0; ks < 32; ks++){
    bf16x8 av = ldfrag(ap);  ap  += 16;
    bf16x8 b0 = ldfrag(bp0); bp0 += 16;
    bf16x8 b1 = ldfrag(bp1); bp1 += 16;
    bf16x8 b2 = ldfrag(bp2); bp2 += 16;
    bf16x8 b3 = ldfrag(bp3); bp3 += 16;
    acc[0] = __builtin_amdgcn_mfma_f32_32x32x16_bf16(av, b0, acc[0], 0, 0, 0);
    acc[1] = __builtin_amdgcn_mfma_f32_32x32x16_bf16(av, b1, acc[1], 0, 0, 0);
    acc[2] = __builtin_amdgcn_mfma_f32_32x32x16_bf16(av, b2, acc[2], 0, 0, 0);
    acc[3] = __builtin_amdgcn_mfma_f32_32x32x16_bf16(av, b3, acc[3], 0, 0, 0);
  }
  int rbase = mb * 128 + wv * 32 + 4 * hi5;
  #pragma unroll
  for (int nt = 0; nt < 4; nt++){
    int col = nb * 128 + nt * 32 + l31;
    float bv = bias[col];
    #pragma unroll
    for (int r = 0; r < 16; r++){
      int row = rbase + (r & 3) + 8 * (r >> 2);
      if (row < VOCAB) E[(u32)row * FOURH + col] = f2bf(acc[nt][r] + bv);
    }
  }
}

// ---- persistent LSTM scan: batch-group replication, group-local exchange ----
// 64 blocks x 512 threads. group g = blockIdx&7 owns batch rows [g*8,g*8+8);
// slice s = blockIdx>>3 computes dims [s*64,s*64+64) (256 gate cols) for them.
// Wh slice held in 128 VGPRs per thread (loaded once - the R2 asset).
// h exchange is group-local: publish 2 KB/block, stage 16 KB/block per step,
// all via R2-proven relaxed agent-scope (MALL) atomics. ~1.2 MB/step total
// MALL traffic vs R2's ~16 MB/step. Double-buffered hbuf + monotone flags;
// publish-h -> syncthreads (vmcnt drain) -> flag store -> poll peers -> stage.
// Safety: peer can only overwrite parity p after all peers' flags prove they
// staged parity p (flag t+2 is published after the stage of parity (t+1)&1).
// MFMA 16x16x32 (m89-verified layouts): A row=l&15, k=(l>>4)*8+j;
// B col=l&15 (col&7 = batch row, cols 8-15 duplicates), same k;
// C/D col=l&15, row=(l>>4)*4+reg -> gate=reg, dim=sub*4+(l>>4).
__launch_bounds__(512, 2)
__global__ void k_scan(const int* __restrict__ cap, const u16* __restrict__ E,
                       const u16* __restrict__ WhT, const float* __restrict__ h0,
                       u32* __restrict__ hbuf, u32* flags, float* __restrict__ out){
  __shared__ __align__(16) u16 hls[2][RPG][LPAD];   // [0]=hi plane, [1]=lo plane

  const int bid = blockIdx.x;
  const int g = bid & 7, s = bid >> 3;
  const int tid = threadIdx.x;
  const int w = tid >> 6, l = tid & 63;
  const int li = l & 15, lg4 = l >> 4;
  const int n  = li & 7;                  // batch row within group
  const int gr0 = g * RPG;                // global row base
  const int dwW = s * 64 + w * 8;         // wave's dim base

  // ---- Wh slice -> registers (once; A row rho=li -> gate col gate*512+dim) ----
  const int gate = li & 3, doff = li >> 2;
  bf16x8 wreg[2][16];
  #pragma unroll
  for (int sub = 0; sub < 2; sub++){
    const u16* wb = WhT + (u32)(gate * 512 + dwW + sub * 4 + doff) * DIM + lg4 * 8;
    #pragma unroll
    for (int ks = 0; ks < 16; ks++)
      wreg[sub][ks] = ldfrag(wb + ks * 32);
  }

  // ---- stage h0 into LDS planes ----
  {
    int r = tid >> 6, d0 = (tid & 63) * 8;
    const float* hp = h0 + (u32)(gr0 + r) * HID + d0;
    u16 hh[8], ll[8];
    #pragma unroll
    for (int k2 = 0; k2 < 8; k2++){
      float f = hp[k2];
      u16 hb = f2bf(f);
      hh[k2] = hb;
      ll[k2] = f2bf(f - bf2f(hb));
    }
    u32x4 qh, ql;
    qh[0] = (u32)hh[0] | ((u32)hh[1] << 16);
    qh[1] = (u32)hh[2] | ((u32)hh[3] << 16);
    qh[2] = (u32)hh[4] | ((u32)hh[5] << 16);
    qh[3] = (u32)hh[6] | ((u32)hh[7] << 16);
    ql[0] = (u32)ll[0] | ((u32)ll[1] << 16);
    ql[1] = (u32)ll[2] | ((u32)ll[3] << 16);
    ql[2] = (u32)ll[4] | ((u32)ll[5] << 16);
    ql[3] = (u32)ll[6] | ((u32)ll[7] << 16);
    *(u32x4*)&hls[0][r][d0] = qh;
    *(u32x4*)&hls[1][r][d0] = ql;
  }
  __syncthreads();

  // ---- E prefetch for t=0 (cap pipeline 2-deep) ----
  u32 ev[8];
  {
    int cap0 = cap[(u32)(gr0 + n) * T1];
    #pragma unroll
    for (int sub = 0; sub < 2; sub++)
      #pragma unroll
      for (int gt = 0; gt < 4; gt++)
        ev[sub*4+gt] = (u32)E[(u32)cap0 * FOURH + gt * 512 + dwW + sub * 4 + lg4];
  }
  int capn1 = cap[(u32)(gr0 + n) * T1 + 1];

  float cst0 = 0.f, cst1 = 0.f;

  for (int t = 0; t < T_STEPS; t++){
    // ---- K-loop: acc = h . WhSlice (hi + lo planes), E added at cell ----
    f32x4 ah0 = {}, ah1 = {}, al0 = {}, al1 = {};
    #pragma unroll
    for (int ks = 0; ks < 16; ks++){
      bf16x8 bh = ldfrag(&hls[0][n][ks * 32 + lg4 * 8]);
      bf16x8 bl = ldfrag(&hls[1][n][ks * 32 + lg4 * 8]);
      ah0 = __builtin_amdgcn_mfma_f32_16x16x32_bf16(wreg[0][ks], bh, ah0, 0, 0, 0);
      ah1 = __builtin_amdgcn_mfma_f32_16x16x32_bf16(wreg[1][ks], bh, ah1, 0, 0, 0);
      al0 = __builtin_amdgcn_mfma_f32_16x16x32_bf16(wreg[0][ks], bl, al0, 0, 0, 0);
      al1 = __builtin_amdgcn_mfma_f32_16x16x32_bf16(wreg[1][ks], bl, al1, 0, 0, 0);
    }

    // ---- LSTM cell (gate = reg; dims dwW + sub*4 + lg4) ----
    float hv0, hv1;
    {
      float ai = ah0[0] + al0[0] + bf2f((u16)ev[0]);
      float af = ah0[1] + al0[1] + bf2f((u16)ev[1]);
      float ao = ah0[2] + al0[2] + bf2f((u16)ev[2]);
      float ag = ah0[3] + al0[3] + bf2f((u16)ev[3]);
      float ig = fsig(ai), fg = fsig(af), og = fsig(ao), gg = ftanh(ag);
      cst0 = fg * cst0 + ig * gg;
      hv0 = og * ftanh(cst0);
    }
    {
      float ai = ah1[0] + al1[0] + bf2f((u16)ev[4]);
      float af = ah1[1] + al1[1] + bf2f((u16)ev[5]);
      float ao = ah1[2] + al1[2] + bf2f((u16)ev[6]);
      float ag = ah1[3] + al1[3] + bf2f((u16)ev[7]);
      float ig = fsig(ai), fg = fsig(af), og = fsig(ao), gg = ftanh(ag);
      cst1 = fg * cst1 + ig * gg;
      hv1 = og * ftanh(cst1);
    }

    // ---- publish h_{t+1}: u64 pairs (dims d,d+1), dims d+1 via shfl ----
    const int ph = (t + 1) & 1;
    u32 pk0 = packhl(hv0), pk1 = packhl(hv1);
    u32 pr0 = (u32)__shfl_down((int)pk0, 16);
    u32 pr1 = (u32)__shfl_down((int)pk1, 16);
    if (t < T_STEPS - 1 && li < 8 && (lg4 & 1) == 0){
      u32* dst = hbuf + (u32)ph * (N_B * HID) + (u32)(gr0 + n) * HID + dwW;
      u64 v0 = (u64)pk0 | ((u64)pr0 << 32);
      u64 v1 = (u64)pk1 | ((u64)pr1 << 32);
      __hip_atomic_store((u64*)(dst + lg4),     v0, __ATOMIC_RELAXED, __HIP_MEMORY_SCOPE_AGENT);
      __hip_atomic_store((u64*)(dst + 4 + lg4), v1, __ATOMIC_RELAXED, __HIP_MEMORY_SCOPE_AGENT);
    }
    // ---- out stores (fp32, write-only stream) ----
    if (li < 8){
      float* ob = out + (u32)(gr0 + n) * (T_STEPS * HID) + (u32)t * HID + dwW;
      __builtin_nontemporal_store(hv0, ob + lg4);
      __builtin_nontemporal_store(hv1, ob + 4 + lg4);
    }
    __syncthreads();     // every wave drains vmcnt -> publish at MALL

    if (t < T_STEPS - 1){
      const u32 want = (u32)(t + 1);
      if (tid == 0)
        __hip_atomic_store(&flags[bid * FLGSTR], want,
                           __ATOMIC_RELAXED, __HIP_MEMORY_SCOPE_AGENT);
      // ---- poll group peers (wave0; lane l waits member l&7) ----
      if (tid < 64){
        u32* fp = &flags[(u32)(g + 8 * (l & 7)) * FLGSTR];
        u32 v;
        do {
          v = __hip_atomic_load(fp, __ATOMIC_RELAXED, __HIP_MEMORY_SCOPE_AGENT);
        } while (__ballot(v < want));
      }
      __syncthreads();
      // ---- stage h_{t+1} -> LDS planes (coherent MALL reads) ----
      {
        int r = tid >> 6, d0 = (tid & 63) * 8;
        const u32* src = hbuf + (u32)ph * (N_B * HID) + (u32)(gr0 + r) * HID + d0;
        u64 a0 = __hip_atomic_load((const u64*)(src + 0), __ATOMIC_RELAXED, __HIP_MEMORY_SCOPE_AGENT);
        u64 a1 = __hip_atomic_load((const u64*)(src + 2), __ATOMIC_RELAXED, __HIP_MEMORY_SCOPE_AGENT);
        u64 a2 = __hip_atomic_load((const u64*)(src + 4), __ATOMIC_RELAXED, __HIP_MEMORY_SCOPE_AGENT);
        u64 a3 = __hip_atomic_load((const u64*)(src + 6), __ATOMIC_RELAXED, __HIP_MEMORY_SCOPE_AGENT);
        u32 p0 = (u32)a0, p1 = (u32)(a0 >> 32);
        u32 p2 = (u32)a1, p3 = (u32)(a1 >> 32);
        u32 p4 = (u32)a2, p5 = (u32)(a2 >> 32);
        u32 p6 = (u32)a3, p7 = (u32)(a3 >> 32);
        u32x4 qh, ql;
        qh[0] = (p0 & 0xFFFFu) | (p1 << 16);
        qh[1] = (p2 & 0xFFFFu) | (p3 << 16);
        qh[2] = (p4 & 0xFFFFu) | (p5 << 16);
        qh[3] = (p6 & 0xFFFFu) | (p7 << 16);
        ql[0] = (p0 >> 16) | (p1 & 0xFFFF0000u);
        ql[1] = (p2 >> 16) | (p3 & 0xFFFF0000u);
        ql[2] = (p4 >> 16) | (p5 & 0xFFFF0000u);
        ql[3] = (p6 >> 16) | (p7 & 0xFFFF0000u);
        *(u32x4*)&hls[0][r][d0] = qh;
        *(u32x4*)&hls[1][r][d0] = ql;
      }
      // ---- E prefetch for t+1 (latency hides under next K-loop) ----
      #pragma unroll
      for (int sub = 0; sub < 2; sub++)
        #pragma unroll
        for (int gt = 0; gt < 4; gt++)
          ev[sub*4+gt] = (u32)E[(u32)capn1 * FOURH + gt * 512 + dwW + sub * 4 + lg4];
      int tn = t + 2; if (tn > T_STEPS) tn = T_STEPS;
      capn1 = cap[(u32)(gr0 + n) * T1 + tn];
      __syncthreads();   // stage visible to all waves
    }
  }
}

extern "C" void kernel_launch(void* const* d_in, const int* in_sizes, int n_in,
                              void* d_out, int out_size, void* d_ws, size_t ws_size,
                              hipStream_t stream){
  const int*   cap  = (const int*)d_in[0];
  const float* h0   = (const float*)d_in[1];
  const float* Wemb = (const float*)d_in[2];
  const float* Wx   = (const float*)d_in[3];
  const float* Wh   = (const float*)d_in[4];
  const float* bias = (const float*)d_in[5];
  float* out = (float*)d_out;

  char* ws = (char*)d_ws;
  const size_t OFF_E    = 0;
  const size_t OFF_WXT  = OFF_E    + (size_t)VOCAB * FOURH * 2;   // 40,960,000
  const size_t OFF_WHT  = OFF_WXT  + (size_t)FOURH * DIM * 2;     // +2 MiB
  const size_t OFF_WE16 = OFF_WHT  + (size_t)FOURH * DIM * 2;     // +2 MiB
  const size_t OFF_HBUF = OFF_WE16 + (size_t)VOCAB * DIM * 2;     // +10.24 MB
  const size_t OFF_FLG  = OFF_HBUF + (size_t)2 * N_B * HID * 4;   // +256 KiB

  u16* E    = (u16*)(ws + OFF_E);
  u16* WxT  = (u16*)(ws + OFF_WXT);
  u16* WhT  = (u16*)(ws + OFF_WHT);
  u16* We16 = (u16*)(ws + OFF_WE16);
  u32* hbuf = (u32*)(ws + OFF_HBUF);
  u32* flg  = (u32*)(ws + OFF_FLG);

  hipLaunchKernelGGL(k_transpose, dim3(1024),   dim3(256), 0, stream, Wx, Wh, WxT, WhT);
  hipLaunchKernelGGL(k_wemb,      dim3(10000),  dim3(256), 0, stream, Wemb, We16);
  hipLaunchKernelGGL(k_init,      dim3(8),      dim3(256), 0, stream, flg);
  hipLaunchKernelGGL(k_egemm,     dim3(16, 79), dim3(256), 0, stream, We16, WxT, bias, E);
  hipLaunchKernelGGL(k_scan,      dim3(SBLK),   dim3(512), 0, stream, cap, E, WhT, h0, hbuf, flg, out);
}